// Round 5
// baseline (190.320 us; speedup 1.0000x reference)
//
#include <hip/hip_runtime.h>
#include <hip/hip_fp16.h>

// LBP semantic dependency, channel-difference form, base-2 domain.
//   d'(x,p) = sp(x+p) - sp(x);  db[a,u] = edge + sum_{v!=a,u} sum_t d'-terms
// tp = e^p stored fp16, slice-major tq[t][n][a][v][u] (50KB contiguous slab
// per (n,a,t)). All db quantities in units of ln2.
// R13 = R12 + pass1 LDS-tiled transpose (both-sides-fat-runs):
//   Dead theories: TLP (R9 null), write traffic (R10, -4us only), miss-chain
//   ILP (R12 null). Invariant: one transpose side always had 320-640B runs
//   -> ~2.4 TB/s cap. Fix: 16v x 8a x 160u LDS tile (41KB): global reads
//   5.1KB runs, global writes 5.1KB runs per a-slab. Thread owns fixed
//   (ao,u4) -> fp32 Sum_v partial stays in-register (db1p10, 6.1MB).

#define S    160
#define S2   25600            // 160*160
#define S3   4096000          // 160^3 (per-n slab, elements)
#define TSZ  8192000          // per tensor elements (2*160^3)
#define C2E  1.4426950408889634f

__device__ __forceinline__ float fexp2(float x) { return __builtin_amdgcn_exp2f(x); }
__device__ __forceinline__ float flog2(float x) { return __builtin_amdgcn_logf(x); }
__device__ __forceinline__ float frcp(float x)  { return __builtin_amdgcn_rcpf(x); }
__device__ __forceinline__ float cdb(float x) {
    return fminf(fmaxf(x, -100.f), 100.f);   // keeps exp2 finite; terms saturated anyway
}
__device__ __forceinline__ float sp2t(float tp) { return flog2(1.f + tp); }
__device__ __forceinline__ float Ff(float x, float tp) {
    float tx = fexp2(x);
    return flog2(1.f + tx * tp) - flog2(1.f + tx);
}
// tq element (v,u) of slice (n,a), tensor t:
#define TQ(tq, t, n, a, v, u) \
    (tq)[(long)(t) * TSZ + (long)(n) * S3 + (long)(a) * S2 + (v) * S + (u)]

// ---- pass 1: LDS-tiled (v,a)-transpose. Block = (a-tile of 8, v-tile of 16,
// n, t), 320 threads. Thread = (ao=tid/40, u4=tid%40).
//  read : per v, lanes sweep (ao,u4) -> 5,120B contiguous runs
//  write: per a-slab, 16v x 160u halves = 5,120B contiguous runs
//  partial: thread-private fp32 float4 over its 16 v (precision = R12)
__global__ __launch_bounds__(320)
void k_pass1(const float* __restrict__ s_sib, const float* __restrict__ s_cop,
             const float* __restrict__ s_grd, __half* __restrict__ tq,
             float* __restrict__ db1p)
{
    int bx = blockIdx.x;              // 0..199
    int at = bx / 10, vt = bx % 10;   // a-tile (8 rows), v-tile (16)
    int a0 = at * 8, v0 = vt * 16;
    int n = blockIdx.y;               // 0..1
    int t = blockIdx.z;               // 0..2
    const float* sT = (t == 0) ? s_sib : (t == 1) ? s_cop : s_grd;
    int tid = threadIdx.x;
    int ao = tid / 40, u4 = tid % 40;
    const float* g = sT + (long)n * S3 + (long)(a0 + ao) * S + u4 * 4;

    // LDS tile: [a(8)][v(16)*160 + 8 pad]  (stride 2568 halves = 5136B -> +4 banks/row)
    __shared__ __half tile[8 * 2568];

    float4 acc = make_float4(0.f, 0.f, 0.f, 0.f);
    #pragma unroll
    for (int h = 0; h < 2; ++h) {
        float4 pv[8];                 // 8 misses in flight per batch
        #pragma unroll
        for (int k = 0; k < 8; ++k)
            pv[k] = *(const float4*)(g + (long)(v0 + h * 8 + k) * S2);
        #pragma unroll
        for (int k = 0; k < 8; ++k) {
            int v = h * 8 + k;
            float t0 = fexp2(pv[k].x * C2E), t1 = fexp2(pv[k].y * C2E);
            float t2 = fexp2(pv[k].z * C2E), t3 = fexp2(pv[k].w * C2E);
            acc.x += flog2(1.f + t0); acc.y += flog2(1.f + t1);
            acc.z += flog2(1.f + t2); acc.w += flog2(1.f + t3);
            __half2 h01 = __floats2half2_rn(t0, t1);
            __half2 h23 = __floats2half2_rn(t2, t3);
            uint2 w; w.x = *(unsigned*)&h01; w.y = *(unsigned*)&h23;
            *(uint2*)(&tile[ao * 2568 + v * 160 + u4 * 4]) = w;
        }
    }
    __syncthreads();
    // write out: 8 a-slabs x 640 uint2 (5,120B contiguous each) = 5120 uint2
    __half* dst0 = tq + (long)t * TSZ + (long)n * S3;
    #pragma unroll
    for (int i = 0; i < 16; ++i) {
        int odx = i * 320 + tid;               // 0..5119
        int aa = odx / 640, rem = odx - aa * 640;   // rem = v*40 + u4
        uint2 w = *(const uint2*)(&tile[aa * 2568 + rem * 4]);
        *(uint2*)(dst0 + (long)(a0 + aa) * S2 + (long)v0 * S + rem * 4) = w;
    }
    // db1p[(t*2+n)*10+vt][a][u] = Sum_{v in tile} log2(1+tp(v,u))
    *(float4*)(db1p + (long)((t * 2 + n) * 10 + vt) * S2 + (a0 + ao) * S + u4 * 4) = acc;
}

// ---- reduce 30 partials + edge + exclusion terms -> db1
__global__ __launch_bounds__(256)
void k_reduce1(const float* __restrict__ db1p, const float* __restrict__ s_edge,
               const __half* __restrict__ tq, float* __restrict__ db1)
{
    int flat = blockIdx.x * 256 + threadIdx.x;          // (n*S+a)*S+u
    int u = flat % S; int rest = flat / S; int a = rest % S; int n = rest / S;
    float s = 0.f;
    #pragma unroll
    for (int t = 0; t < 3; ++t)
        #pragma unroll
        for (int vt = 0; vt < 10; ++vt)
            s += db1p[(long)((t * 2 + n) * 10 + vt) * S2 + a * S + u];
    float r = s_edge[n * S2 + u * S + a] * C2E + s - 480.f;   // -1 per (t,v): 3*160
    for (int t = 0; t < 3; ++t) {
        float tpa = __half2float(TQ(tq, t, n, a, a, u));      // tp(v=a, u)
        r -= (sp2t(tpa) - 1.f);
        if (u != a) {
            float tpu = __half2float(TQ(tq, t, n, a, u, u));  // tp(u,u)
            r -= (sp2t(tpu) - 1.f);
        }
    }
    db1[flat] = r;
}

// ---- phase 2 (+inline di2): db2[u] = di2[u] + sum_{t,v} F(db1[v]-sp2t(tp(u,v)), tp(v,u))
__global__ __launch_bounds__(256)
void k_ph2(const __half* __restrict__ tq, const float* __restrict__ db1c,
           const float* __restrict__ s_edge, float* __restrict__ db2)
{
    int bid = blockIdx.x;
    int slice = bid % 320;      // same-slice blocks -> same XCD (320 % 8 == 0)
    int q = bid / 320;
    int a = slice % S, n = slice / S;
    int u0 = q * 32;
    int tid = threadIdx.x;
    int uj = tid & 31, vs = tid >> 5;
    __shared__ __half A16[S * 32];      // tp(v, u in block)        (10 KB)
    __shared__ __half B16[32 * 164];    // tp(u in block, v), s=164 (10.5 KB)
    __shared__ float E1[S];             // 2^(db1[v]+1)
    __shared__ float accS[256];
    if (tid < S) E1[tid] = fexp2(cdb(db1c[slice * S + tid]) + 1.f);
    float di2r = 0.f;                   // inline di2 for u = u0+tid (tid<32)
    if (tid < 32) {
        int u = u0 + tid;
        float db1a1 = cdb(db1c[slice * S + a]) + 1.f;
        float db1u1 = cdb(db1c[slice * S + u]) + 1.f;
        float sum = 0.f;
        for (int t = 0; t < 3; ++t) {
            float tpa  = __half2float(TQ(tq, t, n, a, a, u));     // tp(v=a, u)
            float tpba = __half2float(TQ(tq, t, n, a, u, a));     // tp(u, v=a)
            sum += Ff(db1a1 - sp2t(tpba), tpa);                   // C2(v=a)
            if (u != a) {
                float tpu = __half2float(TQ(tq, t, n, a, u, u));
                sum += Ff(db1u1 - sp2t(tpu), tpu);                // C2(v=u)
            }
        }
        di2r = s_edge[n * S2 + u * S + a] * C2E - sum;
    }
    float acc = 0.f;
    const __half* slab0 = tq + (long)n * S3 + (long)a * S2;   // 50KB contiguous/t
    for (int t = 0; t < 3; ++t) {
        const __half* slab = slab0 + (long)t * TSZ;
        __syncthreads();
        for (int e = tid; e < 640; e += 256) {    // A: 160 rows x 4 half8 (64B/row)
            int row = e >> 2, c = e & 3;
            *(float4*)(&A16[e * 8]) = *(const float4*)(slab + row * S + u0 + c * 8);
        }
        for (int e = tid; e < 1280; e += 256) {   // B: rows u0..u0+31 = 10KB contiguous
            int r = e / 40, c = e - r * 40;
            *(uint2*)(&B16[r * 164 + c * 4]) = *(const uint2*)(slab + (u0 + r) * S + c * 4);
        }
        __syncthreads();
        #pragma unroll
        for (int k = 0; k < 20; ++k) {
            int vi = k * 8 + vs;
            float tA = __half2float(A16[k * 256 + tid]);
            float tB = __half2float(B16[uj * 164 + vi]);
            float e  = E1[vi] * frcp(1.f + tB);   // 2^(db1[v]+1 - sp2t(tB))
            acc += flog2(1.f + e * tA) - flog2(1.f + e);
        }
    }
    accS[tid] = acc; __syncthreads();
    if (tid < 32) {
        float s = di2r;
        #pragma unroll
        for (int j = 0; j < 8; ++j) s += accS[j * 32 + tid];
        db2[slice * S + u0 + tid] = s;
    }
}

// ---- phase 3 (+inline di3) + output
__global__ __launch_bounds__(256)
void k_ph3(const __half* __restrict__ tq, const float* __restrict__ db1c,
           const float* __restrict__ db2, const float* __restrict__ s_edge,
           float* __restrict__ outp)
{
    int bid = blockIdx.x;
    int slice = bid % 320;
    int q = bid / 320;
    int a = slice % S, n = slice / S;
    int u0 = q * 32;
    int tid = threadIdx.x;
    int uj = tid & 31, vs = tid >> 5;
    int ug = u0 + uj;
    __shared__ __half A16[S * 32];
    __shared__ __half B16[32 * 164];
    __shared__ float E2[S];             // 2^db2[v]
    __shared__ float accS[256];
    if (tid < S) E2[tid] = fexp2(cdb(db2[slice * S + tid]));
    float di3r = 0.f;                   // inline di3 for u = u0+tid (tid<32)
    if (tid < 32) {
        int u = u0 + tid;
        float db1u1 = cdb(db1c[slice * S + u]) + 1.f;
        float db2a = cdb(db2[slice * S + a]);
        float db2u = cdb(db2[slice * S + u]);
        float sum = 0.f;
        for (int t = 0; t < 3; ++t) {
            float tpa  = __half2float(TQ(tq, t, n, a, a, u));     // tp(v=a, u)
            float tpba = __half2float(TQ(tq, t, n, a, u, a));     // tp(u, v=a)
            float d2vu = Ff(db1u1 - sp2t(tpa), tpba);
            sum += Ff(db2a - d2vu, tpa);                          // C3(v=a)
            if (u != a) {
                float tpu = __half2float(TQ(tq, t, n, a, u, u));
                float d2  = Ff(db1u1 - sp2t(tpu), tpu);
                sum += Ff(db2u - d2, tpu);                        // C3(v=u)
            }
        }
        di3r = s_edge[n * S2 + u * S + a] * C2E - sum;
    }
    float E1u = fexp2(cdb(db1c[slice * S + ug]) + 1.f);   // 2^(db1[u]+1)
    float acc = 0.f;
    const __half* slab0 = tq + (long)n * S3 + (long)a * S2;
    for (int t = 0; t < 3; ++t) {
        const __half* slab = slab0 + (long)t * TSZ;
        __syncthreads();
        for (int e = tid; e < 640; e += 256) {
            int row = e >> 2, c = e & 3;
            *(float4*)(&A16[e * 8]) = *(const float4*)(slab + row * S + u0 + c * 8);
        }
        for (int e = tid; e < 1280; e += 256) {
            int r = e / 40, c = e - r * 40;
            *(uint2*)(&B16[r * 164 + c * 4]) = *(const uint2*)(slab + (u0 + r) * S + c * 4);
        }
        __syncthreads();
        #pragma unroll
        for (int k = 0; k < 20; ++k) {
            int vi = k * 8 + vs;
            float tA = __half2float(A16[k * 256 + tid]);   // tp(v,u)
            float tB = __half2float(B16[uj * 164 + vi]);   // tp(u,v)
            float rA = frcp(1.f + tA);
            float e2 = E1u * rA;                           // 2^(db1[u]+1-sp2t(tA))
            float w  = frcp(1.f + e2 * tB);
            float e3 = E2[vi] * ((1.f + e2) * w);          // 2^(db2[v]-d2[v,u])
            acc += flog2(1.f + e3 * tA) - flog2(1.f + e3); // d3[u,v]
        }
    }
    accS[tid] = acc; __syncthreads();
    if (tid < 32) {
        float s = di3r;
        #pragma unroll
        for (int j = 0; j < 8; ++j) s += accS[j * 32 + tid];
        float sc  = fminf(fmaxf(s, -60.f), 60.f);   // avoid exp2 overflow -> inf*0=NaN
        float tsg = fexp2(-sc);
        float r   = __fdividef(1.f, 1.f + tsg);
        long ob = ((long)(n * S + u0 + tid) * S + a) * 2;
        outp[ob]     = tsg * r;
        outp[ob + 1] = r;
    }
}

extern "C" void kernel_launch(void* const* d_in, const int* in_sizes, int n_in,
                              void* d_out, int out_size, void* d_ws, size_t ws_size,
                              hipStream_t stream) {
    const float* s_edge = (const float*)d_in[0];
    const float* s_sib  = (const float*)d_in[1];
    const float* s_cop  = (const float*)d_in[2];
    const float* s_grd  = (const float*)d_in[3];
    float* outp = (float*)d_out;

    __half* tq   = (__half*)d_ws;                            // 49,152,000 B
    float*  db1p = (float*)((char*)d_ws + 49152000);         // 6,144,000 B
    float*  db1  = db1p + 1536000;                           // 204,800 B
    float*  db2  = db1 + 51200;                              // total ~55.7 MB

    k_pass1<<<dim3(200, 2, 3), 320, 0, stream>>>(s_sib, s_cop, s_grd, tq, db1p);
    k_reduce1<<<200, 256, 0, stream>>>(db1p, s_edge, tq, db1);
    k_ph2<<<1600, 256, 0, stream>>>(tq, db1, s_edge, db2);
    k_ph3<<<1600, 256, 0, stream>>>(tq, db1, db2, s_edge, outp);
}

// Round 6
// 165.317 us; speedup vs baseline: 1.1512x; 1.1512x over previous
//
#include <hip/hip_runtime.h>
#include <hip/hip_fp16.h>

// LBP semantic dependency, channel-difference form, base-2 domain.
//   d'(x,p) = sp(x+p) - sp(x);  db[a,u] = edge + sum_{v!=a,u} sum_t d'-terms
// All db quantities in units of ln2. tp = e^p quantized to fp16 (same
// quantization point as the old global tq, so numerics match R13).
// R14 = FULL FUSION. The computation is slice-local: db1/db2/d3/output for
// slice (n,a) need only s_*[n][:][a][:] + s_edge[n][:][a]. One block per
// slice stages all 3 tp-slabs in LDS (155.5KB) and runs ph1->db1->d2->db2
// ->d3->out in-block. Eliminates tq (49MB W + ~100MB R), db1p, 3 launches,
// and ALL workspace use. Rationale: 5 pass1 variants (TLP/traffic/ILP/
// run-length) all pinned at 40-45us; budget closes as ~120us harness
// poison-fill (3 x 40.5us 256MiB fills) + ~65us kernels. Fusion attacks
// the controllable half; zero workspace may also shrink the poison cost.

#define S    160
#define S2   25600            // 160*160
#define S3   4096000          // 160^3 (per-n slab, elements)
#define STR  162              // LDS slab row stride in halves (pad: 2-way banks)
#define C2E  1.4426950408889634f

__device__ __forceinline__ float fexp2(float x) { return __builtin_amdgcn_exp2f(x); }
__device__ __forceinline__ float flog2(float x) { return __builtin_amdgcn_logf(x); }
__device__ __forceinline__ float frcp(float x)  { return __builtin_amdgcn_rcpf(x); }
__device__ __forceinline__ float cdb(float x) {
    return fminf(fmaxf(x, -100.f), 100.f);   // keeps exp2 finite; terms saturated anyway
}
__device__ __forceinline__ float sp2t(float tp) { return flog2(1.f + tp); }
__device__ __forceinline__ float Ff(float x, float tp) {
    float tx = fexp2(x);
    return flog2(1.f + tx * tp) - flog2(1.f + tx);
}

// One block per slice (n,a). 960 threads (15 waves), 1 block/CU (LDS-bound).
// LDS budget: 155,520 (tp3) + 5,120 (red) + 2,560 (db/E) = 163,200 <= 163,840.
__global__ __launch_bounds__(960)
void k_fused(const float* __restrict__ s_sib, const float* __restrict__ s_cop,
             const float* __restrict__ s_grd, const float* __restrict__ s_edge,
             float* __restrict__ outp)
{
    int slice = blockIdx.x;           // 0..319
    int a = slice % S, n = slice / S;
    int tid = threadIdx.x;

    __shared__ __half tp3[3 * S * STR];   // tp3[t][v][u] at t*S*STR + v*STR + u
    __shared__ float  red[1280];          // reduce scratch (ph1: 320 float4)
    __shared__ float  db1[S];
    __shared__ float  db2[S];
    __shared__ float  E1[S];
    __shared__ float  E2[S];

    // ---- stage 3 slabs (fp32 -> tp fp16 in LDS) + ph1 fp32 partial.
    // tid<640: thread = (u4 = tid%40 float4-column, vsg = tid/40 in 0..15).
    // Reads: per v one 640B contiguous run (source [n][v][a][0..160)).
    // acc (fp32, pre-quantization) = Sum over its 30 (t,v) of log2(1+tp).
    float4 acc = make_float4(0.f, 0.f, 0.f, 0.f);
    int u4 = tid % 40, vsg = tid / 40;    // vsg 0..23 (only <16 stage)
    if (tid < 640) {
        #pragma unroll
        for (int t = 0; t < 3; ++t) {
            const float* sT = (t == 0) ? s_sib : (t == 1) ? s_cop : s_grd;
            const float* g = sT + (long)n * S3 + (long)a * S + u4 * 4;
            float4 pv[10];                // all 10 misses in flight
            #pragma unroll
            for (int j = 0; j < 10; ++j)
                pv[j] = *(const float4*)(g + (long)(j * 16 + vsg) * S2);
            #pragma unroll
            for (int j = 0; j < 10; ++j) {
                int v = j * 16 + vsg;
                float t0 = fexp2(pv[j].x * C2E), t1 = fexp2(pv[j].y * C2E);
                float t2 = fexp2(pv[j].z * C2E), t3 = fexp2(pv[j].w * C2E);
                acc.x += flog2(1.f + t0); acc.y += flog2(1.f + t1);
                acc.z += flog2(1.f + t2); acc.w += flog2(1.f + t3);
                __half* b = &tp3[t * (S * STR) + v * STR + u4 * 4];  // 4B-aligned
                *(__half2*)(b)     = __floats2half2_rn(t0, t1);
                *(__half2*)(b + 2) = __floats2half2_rn(t2, t3);
            }
        }
    }
    __syncthreads();

    // ---- ph1 reduce over vsg (16 -> 1, halving through red as float4)
    float4* red4 = (float4*)red;
    #pragma unroll
    for (int r = 8; r >= 1; r >>= 1) {
        if (tid < 640 && vsg >= r && vsg < 2 * r) red4[(vsg - r) * 40 + u4] = acc;
        __syncthreads();
        if (tid < 640 && vsg < r) {
            float4 o = red4[vsg * 40 + u4];
            acc.x += o.x; acc.y += o.y; acc.z += o.z; acc.w += o.w;
        }
        __syncthreads();
    }
    if (tid < 40) {                      // vsg==0 holds full Sum_{t,v}
        db1[tid * 4 + 0] = acc.x; db1[tid * 4 + 1] = acc.y;
        db1[tid * 4 + 2] = acc.z; db1[tid * 4 + 3] = acc.w;
    }
    __syncthreads();

    // ---- db1 finalize (edge + exclusion terms) + E1
    if (tid < S) {
        int u = tid;
        float r = s_edge[n * S2 + u * S + a] * C2E + db1[u] - 480.f;
        #pragma unroll
        for (int t = 0; t < 3; ++t) {
            const __half* sl = &tp3[t * (S * STR)];
            float tpa = __half2float(sl[a * STR + u]);    // tp(v=a, u)
            r -= (sp2t(tpa) - 1.f);
            if (u != a) {
                float tpu = __half2float(sl[u * STR + u]);
                r -= (sp2t(tpu) - 1.f);
            }
        }
        db1[u] = r;
        E1[u] = fexp2(cdb(r) + 1.f);
    }
    __syncthreads();

    // ---- d2 sweep: thread = (u = tid%160, vs = tid/160 in 0..5), v = 6k+vs
    int us = tid % S, vs = tid / S;
    {
        float s = 0.f;
        #pragma unroll
        for (int t = 0; t < 3; ++t) {
            const __half* sl = &tp3[t * (S * STR)];
            for (int k = 0; k < 27; ++k) {
                int v = k * 6 + vs;
                if (v < S) {
                    float tA = __half2float(sl[v * STR + us]);   // tp(v,u) lane-contig
                    float tB = __half2float(sl[us * STR + v]);   // tp(u,v) 2-way
                    float e  = E1[v] * frcp(1.f + tB);
                    s += flog2(1.f + e * tA) - flog2(1.f + e);
                }
            }
        }
        red[vs * S + us] = s;
    }
    __syncthreads();

    // ---- db2 (inline di2) + E2
    if (tid < S) {
        int u = tid;
        float sw = red[u] + red[S + u] + red[2*S + u] + red[3*S + u]
                 + red[4*S + u] + red[5*S + u];
        float db1a1 = cdb(db1[a]) + 1.f;
        float db1u1 = cdb(db1[u]) + 1.f;
        float sum = 0.f;
        #pragma unroll
        for (int t = 0; t < 3; ++t) {
            const __half* sl = &tp3[t * (S * STR)];
            float tpa  = __half2float(sl[a * STR + u]);   // tp(v=a, u)
            float tpba = __half2float(sl[u * STR + a]);   // tp(u, v=a)
            sum += Ff(db1a1 - sp2t(tpba), tpa);           // C2(v=a)
            if (u != a) {
                float tpu = __half2float(sl[u * STR + u]);
                sum += Ff(db1u1 - sp2t(tpu), tpu);        // C2(v=u)
            }
        }
        float d2v = s_edge[n * S2 + u * S + a] * C2E - sum + sw;
        db2[u] = d2v;
        E2[u] = fexp2(cdb(d2v));
    }
    __syncthreads();

    // ---- d3 sweep (same partition)
    {
        float E1u = E1[us];              // 2^(db1[u]+1)
        float s = 0.f;
        #pragma unroll
        for (int t = 0; t < 3; ++t) {
            const __half* sl = &tp3[t * (S * STR)];
            for (int k = 0; k < 27; ++k) {
                int v = k * 6 + vs;
                if (v < S) {
                    float tA = __half2float(sl[v * STR + us]);  // tp(v,u)
                    float tB = __half2float(sl[us * STR + v]);  // tp(u,v)
                    float rA = frcp(1.f + tA);
                    float e2 = E1u * rA;                  // 2^(db1[u]+1-sp2t(tA))
                    float w  = frcp(1.f + e2 * tB);
                    float e3 = E2[v] * ((1.f + e2) * w);  // 2^(db2[v]-d2[v,u])
                    s += flog2(1.f + e3 * tA) - flog2(1.f + e3);
                }
            }
        }
        red[vs * S + us] = s;
    }
    __syncthreads();

    // ---- di3 + output
    if (tid < S) {
        int u = tid;
        float sw = red[u] + red[S + u] + red[2*S + u] + red[3*S + u]
                 + red[4*S + u] + red[5*S + u];
        float db1u1 = cdb(db1[u]) + 1.f;
        float db2a = cdb(db2[a]);
        float db2u = cdb(db2[u]);
        float sum = 0.f;
        #pragma unroll
        for (int t = 0; t < 3; ++t) {
            const __half* sl = &tp3[t * (S * STR)];
            float tpa  = __half2float(sl[a * STR + u]);   // tp(v=a, u)
            float tpba = __half2float(sl[u * STR + a]);   // tp(u, v=a)
            float d2vu = Ff(db1u1 - sp2t(tpa), tpba);
            sum += Ff(db2a - d2vu, tpa);                  // C3(v=a)
            if (u != a) {
                float tpu = __half2float(sl[u * STR + u]);
                float d2  = Ff(db1u1 - sp2t(tpu), tpu);
                sum += Ff(db2u - d2, tpu);                // C3(v=u)
            }
        }
        float s = s_edge[n * S2 + u * S + a] * C2E - sum + sw;
        float sc  = fminf(fmaxf(s, -60.f), 60.f);  // avoid exp2 overflow -> inf*0=NaN
        float tsg = fexp2(-sc);
        float r   = __fdividef(1.f, 1.f + tsg);
        long ob = ((long)(n * S + u) * S + a) * 2;
        *(float2*)(outp + ob) = make_float2(tsg * r, r);
    }
}

extern "C" void kernel_launch(void* const* d_in, const int* in_sizes, int n_in,
                              void* d_out, int out_size, void* d_ws, size_t ws_size,
                              hipStream_t stream) {
    const float* s_edge = (const float*)d_in[0];
    const float* s_sib  = (const float*)d_in[1];
    const float* s_cop  = (const float*)d_in[2];
    const float* s_grd  = (const float*)d_in[3];
    float* outp = (float*)d_out;
    (void)d_ws; (void)ws_size;          // workspace no longer used

    k_fused<<<320, 960, 0, stream>>>(s_sib, s_cop, s_grd, s_edge, outp);
}